// Round 1
// baseline (1016.799 us; speedup 1.0000x reference)
//
#include <hip/hip_runtime.h>
#include <cstdint>

// ---------------------------------------------------------------------------
// dysOpt: Davis-Yin splitting, 262144 rows x 64 vars.
//   A = ones(1,64), b = 32 -> proj_eq(w) = w - (sum(w)-32)/64   (exact /64)
//   lb=0, ub=1 -> proj_box = clamp(z,0,1)
// Reference loop: all rows iterate in lockstep until
//   max_r ||z_new_r - z_r|| <= 0.01  (or 200 iters), i.e. T = max_r T_r
// (residual of an averaged operator is monotone per row).
// Pass 1: per-row iterate to own convergence, atomicMax T, checkpoint z(T_r).
// Pass 2: resume each row T - T_r iters (same trajectory as lockstep ref),
//         one extra differentiable step, clamp, store.
// ---------------------------------------------------------------------------

// JAX >= 0.5 defaults threefry_partitionable=True: per-element uint64 counter
// (hi, lo) = (0, flat_idx), 32-bit draw = out0 ^ out1.
// Legacy (=0) scheme: iota split in halves, pair (i, i+2^23).
#ifndef JAX_PARTITIONABLE
#define JAX_PARTITIONABLE 1
#endif

#define BATCHN 262144
#define MAXIT  200

__device__ __forceinline__ void tf2x32(uint32_t x0, uint32_t x1,
                                       uint32_t& o0, uint32_t& o1) {
  const uint32_t k0 = 0u, k1 = 1u;                 // jax.random.key(1) -> [0,1]
  const uint32_t k2 = 0x1BD11BDAu ^ k0 ^ k1;
  x0 += k0; x1 += k1;
#define TFR(r) { x0 += x1; x1 = (x1 << (r)) | (x1 >> (32 - (r))); x1 ^= x0; }
  TFR(13) TFR(15) TFR(26) TFR(6)   x0 += k1; x1 += k2 + 1u;
  TFR(17) TFR(29) TFR(16) TFR(24)  x0 += k2; x1 += k0 + 2u;
  TFR(13) TFR(15) TFR(26) TFR(6)   x0 += k0; x1 += k1 + 3u;
  TFR(17) TFR(29) TFR(16) TFR(24)  x0 += k1; x1 += k2 + 4u;
  TFR(13) TFR(15) TFR(26) TFR(6)   x0 += k2; x1 += k0 + 5u;
#undef TFR
  o0 = x0; o1 = x1;
}

__device__ __forceinline__ float z0_at(uint32_t f) {
  uint32_t b;
#if JAX_PARTITIONABLE
  uint32_t o0, o1;
  tf2x32(0u, f, o0, o1);
  b = o0 ^ o1;
#else
  const uint32_t H = 8388608u;  // 2^23 = half of 2^24 draws
  uint32_t lo = (f < H) ? f : (f - H);
  uint32_t o0, o1;
  tf2x32(lo, lo + H, o0, o1);
  b = (f < H) ? o0 : o1;
#endif
  // uniform [0,1): bitcast((bits>>9)|0x3f800000) - 1 ; z0 = u*(1-0)+0 = u
  return __uint_as_float((b >> 9) | 0x3f800000u) - 1.0f;
}

// One DYS step on 8 register-resident elements; row = 8 lanes (xor 1,2,4).
// Uses _rn intrinsics to forbid FMA contraction (XLA emits unfused mul/add).
// Returns row sum of squared diff (replicated across the 8 lanes) if wantDiff.
__device__ __forceinline__ float dys_iter(float z[8], const float c[8],
                                          bool wantDiff) {
  float x[8], w[8];
  float sv = 0.0f;
#pragma unroll
  for (int j = 0; j < 8; ++j) {
    float xx = fminf(fmaxf(z[j], 0.0f), 1.0f);          // proj_box
    float grad = __fadd_rn(c[j], __fmul_rn(0.05f, xx)); // cost + ALPHA*x
    float t  = __fsub_rn(__fmul_rn(2.0f, xx), z[j]);    // 2x - z
    float ww = __fsub_rn(t, __fmul_rn(0.05f, grad));    // - ALPHA*grad
    x[j] = xx; w[j] = ww;
    sv = __fadd_rn(sv, ww);
  }
  sv += __shfl_xor(sv, 1);
  sv += __shfl_xor(sv, 2);
  sv += __shfl_xor(sv, 4);
  float corr = __fmul_rn(__fsub_rn(sv, 32.0f), 0.015625f);  // (sum-32)/64 exact
  float ds = 0.0f;
#pragma unroll
  for (int j = 0; j < 8; ++j) {
    float y  = __fsub_rn(w[j], corr);                   // proj_eq
    float zn = __fadd_rn(__fsub_rn(z[j], x[j]), y);     // z - x + y
    if (wantDiff) {
      float d = __fsub_rn(zn, z[j]);
      ds = __fadd_rn(ds, __fmul_rn(d, d));
    }
    z[j] = zn;
  }
  if (wantDiff) {
    ds += __shfl_xor(ds, 1);
    ds += __shfl_xor(ds, 2);
    ds += __shfl_xor(ds, 4);
  }
  return ds;
}

template <int STORE>
__global__ __launch_bounds__(256) void dys_pass1(
    const float* __restrict__ cost, int* __restrict__ Tglob,
    int* __restrict__ TrArr, float* __restrict__ zst) {
  const int t = threadIdx.x;
  const int row = blockIdx.x * 32 + (t >> 3);
  const int base = row * 64 + (t & 7) * 8;

  float c[8], z[8];
  const float4 c0 = *(const float4*)(cost + base);
  const float4 c1 = *(const float4*)(cost + base + 4);
  c[0] = c0.x; c[1] = c0.y; c[2] = c0.z; c[3] = c0.w;
  c[4] = c1.x; c[5] = c1.y; c[6] = c1.z; c[7] = c1.w;
#pragma unroll
  for (int j = 0; j < 8; ++j) z[j] = z0_at((uint32_t)(base + j));

  int Tr = 0;
  for (int i = 1; i <= MAXIT; ++i) {
    float ds = dys_iter(z, c, true);
    if (Tr == 0 && sqrtf(ds) <= 0.01f) {   // ref: stop when diff <= TOL
      Tr = i;
      if (STORE) {
        *(float4*)(zst + base)     = make_float4(z[0], z[1], z[2], z[3]);
        *(float4*)(zst + base + 4) = make_float4(z[4], z[5], z[6], z[7]);
      }
    }
    if (__all(Tr != 0)) break;             // whole wave (8 rows) done
  }
  if (Tr == 0) {
    Tr = MAXIT;
    if (STORE) {
      *(float4*)(zst + base)     = make_float4(z[0], z[1], z[2], z[3]);
      *(float4*)(zst + base + 4) = make_float4(z[4], z[5], z[6], z[7]);
    }
  }
  if (STORE && (t & 7) == 0) TrArr[row] = Tr;

  int m = Tr;
  m = max(m, __shfl_xor(m, 1));  m = max(m, __shfl_xor(m, 2));
  m = max(m, __shfl_xor(m, 4));  m = max(m, __shfl_xor(m, 8));
  m = max(m, __shfl_xor(m, 16)); m = max(m, __shfl_xor(m, 32));
  if ((t & 63) == 0) atomicMax(Tglob, m);
}

template <int STORE>
__global__ __launch_bounds__(256) void dys_pass2(
    const float* __restrict__ cost, const int* __restrict__ Tglob,
    const int* __restrict__ TrArr, const float* __restrict__ zst,
    float* __restrict__ out) {
  const int t = threadIdx.x;
  const int row = blockIdx.x * 32 + (t >> 3);
  const int base = row * 64 + (t & 7) * 8;

  float c[8], z[8];
  const float4 c0 = *(const float4*)(cost + base);
  const float4 c1 = *(const float4*)(cost + base + 4);
  c[0] = c0.x; c[1] = c0.y; c[2] = c0.z; c[3] = c0.w;
  c[4] = c1.x; c[5] = c1.y; c[6] = c1.z; c[7] = c1.w;

  const int T = *Tglob;
  int start;
  if (STORE) {
    const float4 za = *(const float4*)(zst + base);
    const float4 zb = *(const float4*)(zst + base + 4);
    z[0] = za.x; z[1] = za.y; z[2] = za.z; z[3] = za.w;
    z[4] = zb.x; z[5] = zb.y; z[6] = zb.z; z[7] = zb.w;
    start = TrArr[row];
  } else {
#pragma unroll
    for (int j = 0; j < 8; ++j) z[j] = z0_at((uint32_t)(base + j));
    start = 0;
  }

  // continue the lockstep trajectory to global T (shuffle partners stay
  // within the 8-lane row group, which shares `start` -> safe divergence)
  for (int i = start; i < T; ++i) dys_iter(z, c, false);

  dys_iter(z, c, false);  // the one extra differentiable DYS step

  float4 oa, ob;
  oa.x = fminf(fmaxf(z[0], 0.0f), 1.0f);
  oa.y = fminf(fmaxf(z[1], 0.0f), 1.0f);
  oa.z = fminf(fmaxf(z[2], 0.0f), 1.0f);
  oa.w = fminf(fmaxf(z[3], 0.0f), 1.0f);
  ob.x = fminf(fmaxf(z[4], 0.0f), 1.0f);
  ob.y = fminf(fmaxf(z[5], 0.0f), 1.0f);
  ob.z = fminf(fmaxf(z[6], 0.0f), 1.0f);
  ob.w = fminf(fmaxf(z[7], 0.0f), 1.0f);
  *(float4*)(out + base)     = oa;
  *(float4*)(out + base + 4) = ob;
}

extern "C" void kernel_launch(void* const* d_in, const int* in_sizes, int n_in,
                              void* d_out, int out_size, void* d_ws,
                              size_t ws_size, hipStream_t stream) {
  const float* cost = (const float*)d_in[0];
  float* out = (float*)d_out;

  // ws layout: [0..4) int T ; [1KB .. 1KB+1MB) Tr per row ; [~1MB..] z ckpt
  int* Tglob = (int*)d_ws;
  const size_t TR_OFF = 1024;
  const size_t Z_OFF  = TR_OFF + (size_t)BATCHN * sizeof(int);  // 16B aligned
  int*   TrArr = (int*)((char*)d_ws + TR_OFF);
  float* zst   = (float*)((char*)d_ws + Z_OFF);
  const size_t need = Z_OFF + (size_t)BATCHN * 64 * sizeof(float); // ~65 MB
  const bool store = (ws_size >= need);

  hipMemsetAsync(Tglob, 0, sizeof(int), stream);  // poison-safe init of T

  dim3 grid(BATCHN / 32), block(256);
  if (store) {
    dys_pass1<1><<<grid, block, 0, stream>>>(cost, Tglob, TrArr, zst);
    dys_pass2<1><<<grid, block, 0, stream>>>(cost, Tglob, TrArr, zst, out);
  } else {
    dys_pass1<0><<<grid, block, 0, stream>>>(cost, Tglob, nullptr, nullptr);
    dys_pass2<0><<<grid, block, 0, stream>>>(cost, Tglob, nullptr, nullptr, out);
  }
}

// Round 2
// 751.663 us; speedup vs baseline: 1.3527x; 1.3527x over previous
//
#include <hip/hip_runtime.h>
#include <cstdint>

// ---------------------------------------------------------------------------
// dysOpt: Davis-Yin splitting, 262144 rows x 64 vars.
//   proj_eq(w) = w - (sum(w)-32)/64 ; proj_box = clamp(z,0,1)
// Reference: lockstep until max_r ||dz_r|| <= 0.01 or 200 iters -> T = max Tr.
// Pass1: per-wave (8 rows) iterate until all 8 converged (or 200) = i_break;
//        store z(i_break) + i_break (wave-uniform), atomicMax global T.
//        (Converged rows keep updating until i_break -- matches the lockstep
//        reference trajectory, so the checkpoint is exact.)
// Pass2: resume from i_break to T (usually 0..few iters since T is cap-pinned),
//        one extra differentiable step, clamp, store.
// Rounding: clamp via v_med3 (bit-exact), 2x-z via fma (bit-exact);
//   ALPHA*grad folded to fma(0.0025,x,0.05c) (~1 ulp/iter drift, nonexpansive
//   map keeps accumulated drift ~2e-5 << 0.02 threshold).
// ---------------------------------------------------------------------------

#ifndef JAX_PARTITIONABLE
#define JAX_PARTITIONABLE 1
#endif

#define BATCHN 262144
#define MAXIT  200

__device__ __forceinline__ void tf2x32(uint32_t x0, uint32_t x1,
                                       uint32_t& o0, uint32_t& o1) {
  const uint32_t k0 = 0u, k1 = 1u;                 // jax.random.key(1) -> [0,1]
  const uint32_t k2 = 0x1BD11BDAu ^ k0 ^ k1;
  x0 += k0; x1 += k1;
#define TFR(r) { x0 += x1; x1 = (x1 << (r)) | (x1 >> (32 - (r))); x1 ^= x0; }
  TFR(13) TFR(15) TFR(26) TFR(6)   x0 += k1; x1 += k2 + 1u;
  TFR(17) TFR(29) TFR(16) TFR(24)  x0 += k2; x1 += k0 + 2u;
  TFR(13) TFR(15) TFR(26) TFR(6)   x0 += k0; x1 += k1 + 3u;
  TFR(17) TFR(29) TFR(16) TFR(24)  x0 += k1; x1 += k2 + 4u;
  TFR(13) TFR(15) TFR(26) TFR(6)   x0 += k2; x1 += k0 + 5u;
#undef TFR
  o0 = x0; o1 = x1;
}

__device__ __forceinline__ float z0_at(uint32_t f) {
  uint32_t b;
#if JAX_PARTITIONABLE
  uint32_t o0, o1;
  tf2x32(0u, f, o0, o1);
  b = o0 ^ o1;
#else
  const uint32_t H = 8388608u;
  uint32_t lo = (f < H) ? f : (f - H);
  uint32_t o0, o1;
  tf2x32(lo, lo + H, o0, o1);
  b = (f < H) ? o0 : o1;
#endif
  return __uint_as_float((b >> 9) | 0x3f800000u) - 1.0f;
}

// One DYS step, 8 register elems/lane, row = 8 lanes (xor 1,2,4).
// c05[j] = 0.05*cost[j]. Returns row sum-sq diff (replicated) if WANT.
template <bool WANT>
__device__ __forceinline__ float dys_iter(float z[8], const float c05[8]) {
  float x[8], w[8];
  float sv = 0.0f;
#pragma unroll
  for (int j = 0; j < 8; ++j) {
    float xx  = __builtin_amdgcn_fmed3f(z[j], 0.0f, 1.0f);   // clamp, bit-exact
    float g05 = __builtin_fmaf(0.0025f, xx, c05[j]);         // ALPHA*grad
    float t   = __builtin_fmaf(2.0f, xx, -z[j]);             // 2x-z, bit-exact
    float ww  = t - g05;
    x[j] = xx; w[j] = ww;
    sv += ww;
  }
  sv += __shfl_xor(sv, 1);
  sv += __shfl_xor(sv, 2);
  sv += __shfl_xor(sv, 4);
  float corr = (sv - 32.0f) * 0.015625f;                     // (sum-32)/64
  float ds = 0.0f;
#pragma unroll
  for (int j = 0; j < 8; ++j) {
    float y  = w[j] - corr;
    float zn = (z[j] - x[j]) + y;
    if (WANT) { float d = zn - z[j]; ds = __builtin_fmaf(d, d, ds); }
    z[j] = zn;
  }
  if (WANT) {
    ds += __shfl_xor(ds, 1);
    ds += __shfl_xor(ds, 2);
    ds += __shfl_xor(ds, 4);
  }
  return ds;
}

template <int STORE>
__global__ __launch_bounds__(256) void dys_pass1(
    const float* __restrict__ cost, int* __restrict__ Tglob,
    int* __restrict__ TrArr, float* __restrict__ zst) {
  const int t = threadIdx.x;
  const int row = blockIdx.x * 32 + (t >> 3);
  const int base = row * 64 + (t & 7) * 8;

  float c05[8], z[8];
  const float4 c0 = *(const float4*)(cost + base);
  const float4 c1 = *(const float4*)(cost + base + 4);
  c05[0] = 0.05f * c0.x; c05[1] = 0.05f * c0.y;
  c05[2] = 0.05f * c0.z; c05[3] = 0.05f * c0.w;
  c05[4] = 0.05f * c1.x; c05[5] = 0.05f * c1.y;
  c05[6] = 0.05f * c1.z; c05[7] = 0.05f * c1.w;
#pragma unroll
  for (int j = 0; j < 8; ++j) z[j] = z0_at((uint32_t)(base + j));

  int Tr = 0, ib = MAXIT;
  for (int i = 1; i <= MAXIT; ++i) {
    float ds = dys_iter<true>(z, c05);
    if (Tr == 0 && ds <= 1.0e-4f) Tr = i;   // ||dz|| <= 0.01
    if (__all(Tr != 0)) { ib = i; break; }  // whole wave (8 rows) done
  }
  // z == z(ib), the lockstep trajectory at iteration ib (wave-uniform)
  if (STORE) {
    *(float4*)(zst + base)     = make_float4(z[0], z[1], z[2], z[3]);
    *(float4*)(zst + base + 4) = make_float4(z[4], z[5], z[6], z[7]);
    if ((t & 7) == 0) TrArr[row] = ib;
  }
  if ((t & 63) == 0) atomicMax(Tglob, ib);  // ib = max Tr over wave's rows
}

template <int STORE>
__global__ __launch_bounds__(256) void dys_pass2(
    const float* __restrict__ cost, const int* __restrict__ Tglob,
    const int* __restrict__ TrArr, const float* __restrict__ zst,
    float* __restrict__ out) {
  const int t = threadIdx.x;
  const int row = blockIdx.x * 32 + (t >> 3);
  const int base = row * 64 + (t & 7) * 8;

  float c05[8], z[8];
  const float4 c0 = *(const float4*)(cost + base);
  const float4 c1 = *(const float4*)(cost + base + 4);
  c05[0] = 0.05f * c0.x; c05[1] = 0.05f * c0.y;
  c05[2] = 0.05f * c0.z; c05[3] = 0.05f * c0.w;
  c05[4] = 0.05f * c1.x; c05[5] = 0.05f * c1.y;
  c05[6] = 0.05f * c1.z; c05[7] = 0.05f * c1.w;

  const int T = *Tglob;
  int start;
  if (STORE) {
    const float4 za = *(const float4*)(zst + base);
    const float4 zb = *(const float4*)(zst + base + 4);
    z[0] = za.x; z[1] = za.y; z[2] = za.z; z[3] = za.w;
    z[4] = zb.x; z[5] = zb.y; z[6] = zb.z; z[7] = zb.w;
    start = TrArr[row];            // wave-uniform (stored at wave-break)
  } else {
#pragma unroll
    for (int j = 0; j < 8; ++j) z[j] = z0_at((uint32_t)(base + j));
    start = 0;
  }

  for (int i = start; i < T; ++i) dys_iter<false>(z, c05);

  dys_iter<false>(z, c05);         // the one differentiable DYS step

  float4 oa, ob;
  oa.x = __builtin_amdgcn_fmed3f(z[0], 0.0f, 1.0f);
  oa.y = __builtin_amdgcn_fmed3f(z[1], 0.0f, 1.0f);
  oa.z = __builtin_amdgcn_fmed3f(z[2], 0.0f, 1.0f);
  oa.w = __builtin_amdgcn_fmed3f(z[3], 0.0f, 1.0f);
  ob.x = __builtin_amdgcn_fmed3f(z[4], 0.0f, 1.0f);
  ob.y = __builtin_amdgcn_fmed3f(z[5], 0.0f, 1.0f);
  ob.z = __builtin_amdgcn_fmed3f(z[6], 0.0f, 1.0f);
  ob.w = __builtin_amdgcn_fmed3f(z[7], 0.0f, 1.0f);
  *(float4*)(out + base)     = oa;
  *(float4*)(out + base + 4) = ob;
}

extern "C" void kernel_launch(void* const* d_in, const int* in_sizes, int n_in,
                              void* d_out, int out_size, void* d_ws,
                              size_t ws_size, hipStream_t stream) {
  const float* cost = (const float*)d_in[0];
  float* out = (float*)d_out;

  int* Tglob = (int*)d_ws;
  const size_t TR_OFF = 1024;
  const size_t Z_OFF  = TR_OFF + (size_t)BATCHN * sizeof(int);
  int*   TrArr = (int*)((char*)d_ws + TR_OFF);
  float* zst   = (float*)((char*)d_ws + Z_OFF);
  const size_t need = Z_OFF + (size_t)BATCHN * 64 * sizeof(float); // ~65 MB
  const bool store = (ws_size >= need);

  hipMemsetAsync(Tglob, 0, sizeof(int), stream);

  dim3 grid(BATCHN / 32), block(256);
  if (store) {
    dys_pass1<1><<<grid, block, 0, stream>>>(cost, Tglob, TrArr, zst);
    dys_pass2<1><<<grid, block, 0, stream>>>(cost, Tglob, TrArr, zst, out);
  } else {
    dys_pass1<0><<<grid, block, 0, stream>>>(cost, Tglob, nullptr, nullptr);
    dys_pass2<0><<<grid, block, 0, stream>>>(cost, Tglob, nullptr, nullptr, out);
  }
}

// Round 3
// 714.212 us; speedup vs baseline: 1.4237x; 1.0524x over previous
//
#include <hip/hip_runtime.h>
#include <cstdint>

// ---------------------------------------------------------------------------
// dysOpt: Davis-Yin splitting, 262144 rows x 64 vars.
//   proj_eq(w) = w - (sum(w)-32)/64 ; proj_box = clamp(z,0,1)
// Reference: lockstep until max_r ||dz_r|| <= 0.01 or 200 iters -> T = max Tr.
// Pass1: per-wave (8 rows) iterate until all 8 converged (or 200) = ib;
//        checkpoint z(ib) + ib (wave-uniform), atomicMax global T.
// Pass2: resume ib -> T, one differentiable step, clamp, store.
// Round 3: packed f32 math (v_pk_fma_f32 etc., full-rate on CDNA) via
//          float2 ext-vectors -> ~halves VALU issue count. Packed ops are
//          IEEE RN f32, bit-identical per-op; only the row-sum reduction
//          order changes (~1 ulp in corr, bounded by nonexpansive map).
// ---------------------------------------------------------------------------

#ifndef JAX_PARTITIONABLE
#define JAX_PARTITIONABLE 1
#endif

#define BATCHN 262144
#define MAXIT  200

typedef float v2f __attribute__((ext_vector_type(2)));

__device__ __forceinline__ void tf2x32(uint32_t x0, uint32_t x1,
                                       uint32_t& o0, uint32_t& o1) {
  const uint32_t k0 = 0u, k1 = 1u;                 // jax.random.key(1) -> [0,1]
  const uint32_t k2 = 0x1BD11BDAu ^ k0 ^ k1;
  x0 += k0; x1 += k1;
#define TFR(r) { x0 += x1; x1 = (x1 << (r)) | (x1 >> (32 - (r))); x1 ^= x0; }
  TFR(13) TFR(15) TFR(26) TFR(6)   x0 += k1; x1 += k2 + 1u;
  TFR(17) TFR(29) TFR(16) TFR(24)  x0 += k2; x1 += k0 + 2u;
  TFR(13) TFR(15) TFR(26) TFR(6)   x0 += k0; x1 += k1 + 3u;
  TFR(17) TFR(29) TFR(16) TFR(24)  x0 += k1; x1 += k2 + 4u;
  TFR(13) TFR(15) TFR(26) TFR(6)   x0 += k2; x1 += k0 + 5u;
#undef TFR
  o0 = x0; o1 = x1;
}

__device__ __forceinline__ float z0_at(uint32_t f) {
  uint32_t b;
#if JAX_PARTITIONABLE
  uint32_t o0, o1;
  tf2x32(0u, f, o0, o1);
  b = o0 ^ o1;
#else
  const uint32_t H = 8388608u;
  uint32_t lo = (f < H) ? f : (f - H);
  uint32_t o0, o1;
  tf2x32(lo, lo + H, o0, o1);
  b = (f < H) ? o0 : o1;
#endif
  return __uint_as_float((b >> 9) | 0x3f800000u) - 1.0f;
}

// One DYS step, 8 elems/lane as 4x float2 (packed f32), row = 8 lanes.
// c05[j] = 0.05*cost. Returns row sum-sq diff (replicated) if WANT.
template <bool WANT>
__device__ __forceinline__ float dys_iter(v2f z[4], const v2f c05[4]) {
  v2f x[4], w[4];
  v2f sv2 = (v2f)(0.0f);
#pragma unroll
  for (int j = 0; j < 4; ++j) {
    v2f xx = __builtin_elementwise_max(z[j], (v2f)(0.0f));  // v_pk_max_f32
    xx     = __builtin_elementwise_min(xx,  (v2f)(1.0f));   // v_pk_min_f32
    v2f g05 = __builtin_elementwise_fma((v2f)(0.0025f), xx, c05[j]);
    v2f t   = __builtin_elementwise_fma((v2f)(2.0f), xx, -z[j]);  // exact 2x-z
    v2f ww  = t - g05;
    x[j] = xx; w[j] = ww;
    sv2 += ww;
  }
  float sv = sv2.x + sv2.y;
  sv += __shfl_xor(sv, 1);
  sv += __shfl_xor(sv, 2);
  sv += __shfl_xor(sv, 4);
  float corr = (sv - 32.0f) * 0.015625f;                    // (sum-32)/64 exact
  v2f corr2; corr2.x = corr; corr2.y = corr;
  v2f ds2 = (v2f)(0.0f);
#pragma unroll
  for (int j = 0; j < 4; ++j) {
    v2f y  = w[j] - corr2;                                  // proj_eq
    v2f zn = (z[j] - x[j]) + y;                             // z - x + y
    if (WANT) {
      v2f d = zn - z[j];
      ds2 = __builtin_elementwise_fma(d, d, ds2);
    }
    z[j] = zn;
  }
  if (!WANT) return 0.0f;
  float ds = ds2.x + ds2.y;
  ds += __shfl_xor(ds, 1);
  ds += __shfl_xor(ds, 2);
  ds += __shfl_xor(ds, 4);
  return ds;
}

__device__ __forceinline__ void load_c05(const float* __restrict__ cost,
                                         int base, v2f c05[4]) {
  const float4 c0 = *(const float4*)(cost + base);
  const float4 c1 = *(const float4*)(cost + base + 4);
  c05[0].x = 0.05f * c0.x; c05[0].y = 0.05f * c0.y;
  c05[1].x = 0.05f * c0.z; c05[1].y = 0.05f * c0.w;
  c05[2].x = 0.05f * c1.x; c05[2].y = 0.05f * c1.y;
  c05[3].x = 0.05f * c1.z; c05[3].y = 0.05f * c1.w;
}

template <int STORE>
__global__ __launch_bounds__(256) void dys_pass1(
    const float* __restrict__ cost, int* __restrict__ Tglob,
    int* __restrict__ TrArr, float* __restrict__ zst) {
  const int t = threadIdx.x;
  const int row = blockIdx.x * 32 + (t >> 3);
  const int base = row * 64 + (t & 7) * 8;

  v2f c05[4], z[4];
  load_c05(cost, base, c05);
#pragma unroll
  for (int j = 0; j < 4; ++j) {
    z[j].x = z0_at((uint32_t)(base + 2 * j));
    z[j].y = z0_at((uint32_t)(base + 2 * j + 1));
  }

  int Tr = 0, ib = MAXIT;
  for (int i = 1; i <= MAXIT; ++i) {
    float ds = dys_iter<true>(z, c05);
    if (Tr == 0 && ds <= 1.0e-4f) Tr = i;   // ||dz|| <= 0.01
    if (__all(Tr != 0)) { ib = i; break; }  // all 8 rows of the wave done
  }
  // z == lockstep trajectory at iteration ib (wave-uniform)
  if (STORE) {
    *(float4*)(zst + base)     = make_float4(z[0].x, z[0].y, z[1].x, z[1].y);
    *(float4*)(zst + base + 4) = make_float4(z[2].x, z[2].y, z[3].x, z[3].y);
    if ((t & 7) == 0) TrArr[row] = ib;
  }
  if ((t & 63) == 0) atomicMax(Tglob, ib);
}

template <int STORE>
__global__ __launch_bounds__(256) void dys_pass2(
    const float* __restrict__ cost, const int* __restrict__ Tglob,
    const int* __restrict__ TrArr, const float* __restrict__ zst,
    float* __restrict__ out) {
  const int t = threadIdx.x;
  const int row = blockIdx.x * 32 + (t >> 3);
  const int base = row * 64 + (t & 7) * 8;

  v2f c05[4], z[4];
  load_c05(cost, base, c05);

  const int T = *Tglob;
  int start;
  if (STORE) {
    const float4 za = *(const float4*)(zst + base);
    const float4 zb = *(const float4*)(zst + base + 4);
    z[0].x = za.x; z[0].y = za.y; z[1].x = za.z; z[1].y = za.w;
    z[2].x = zb.x; z[2].y = zb.y; z[3].x = zb.z; z[3].y = zb.w;
    start = TrArr[row];            // wave-uniform (stored at wave-break)
  } else {
#pragma unroll
    for (int j = 0; j < 4; ++j) {
      z[j].x = z0_at((uint32_t)(base + 2 * j));
      z[j].y = z0_at((uint32_t)(base + 2 * j + 1));
    }
    start = 0;
  }

  for (int i = start; i < T; ++i) dys_iter<false>(z, c05);

  dys_iter<false>(z, c05);         // the one differentiable DYS step

#pragma unroll
  for (int j = 0; j < 4; ++j) {
    z[j] = __builtin_elementwise_max(z[j], (v2f)(0.0f));
    z[j] = __builtin_elementwise_min(z[j], (v2f)(1.0f));
  }
  *(float4*)(out + base)     = make_float4(z[0].x, z[0].y, z[1].x, z[1].y);
  *(float4*)(out + base + 4) = make_float4(z[2].x, z[2].y, z[3].x, z[3].y);
}

extern "C" void kernel_launch(void* const* d_in, const int* in_sizes, int n_in,
                              void* d_out, int out_size, void* d_ws,
                              size_t ws_size, hipStream_t stream) {
  const float* cost = (const float*)d_in[0];
  float* out = (float*)d_out;

  int* Tglob = (int*)d_ws;
  const size_t TR_OFF = 1024;
  const size_t Z_OFF  = TR_OFF + (size_t)BATCHN * sizeof(int);
  int*   TrArr = (int*)((char*)d_ws + TR_OFF);
  float* zst   = (float*)((char*)d_ws + Z_OFF);
  const size_t need = Z_OFF + (size_t)BATCHN * 64 * sizeof(float); // ~65 MB
  const bool store = (ws_size >= need);

  hipMemsetAsync(Tglob, 0, sizeof(int), stream);

  dim3 grid(BATCHN / 32), block(256);
  if (store) {
    dys_pass1<1><<<grid, block, 0, stream>>>(cost, Tglob, TrArr, zst);
    dys_pass2<1><<<grid, block, 0, stream>>>(cost, Tglob, TrArr, zst, out);
  } else {
    dys_pass1<0><<<grid, block, 0, stream>>>(cost, Tglob, nullptr, nullptr);
    dys_pass2<0><<<grid, block, 0, stream>>>(cost, Tglob, nullptr, nullptr, out);
  }
}

// Round 5
// 511.360 us; speedup vs baseline: 1.9884x; 1.3967x over previous
//
#include <hip/hip_runtime.h>
#include <cstdint>

// ---------------------------------------------------------------------------
// dysOpt: Davis-Yin splitting, 262144 rows x 64 vars. Dynamic T (round-4
// post-mortem: reference's while-loop exits BEFORE the 200 cap; T must be
// computed). Two-pass:
//   Pass1: per-wave (16 rows) iterate until all rows converged (or 200) = ib;
//          checkpoint z(ib) (wave-uniform), atomicMax global T = max_r Tr.
//          (Fixed-point residual of an averaged operator is non-increasing
//          per row -> first-i-all-converged == max of per-row first-i.)
//   Pass2: resume ib -> T, one differentiable step, clamp, store.
// Collapsed iteration (exact algebra, verified round 4 — its failure was the
// T assumption, not the algebra):
//   x  = clamp(z,0,1)
//   z+ = (1-a^2)*x - a*c - corr ,  corr = (K2*Sx - R - 32)/64
//   R  = Sz + a*Sc tracked recursively: R+ = R - Sx + 32.
// Layout: 16 elems/lane, 4 lanes/row, 16 rows/wave -> 6 ops/elem + 4 shfl
// per row-iter. Convergence: row ||dz||^2 <= 1e-4 (TOL=0.01 squared).
// ---------------------------------------------------------------------------

#ifndef JAX_PARTITIONABLE
#define JAX_PARTITIONABLE 1
#endif

#define BATCHN 262144
#define MAXIT  200
#define ROWS_PER_WAVE 16
#define NWAVES (BATCHN / ROWS_PER_WAVE)   // 16384

__device__ __forceinline__ void tf2x32(uint32_t x0, uint32_t x1,
                                       uint32_t& o0, uint32_t& o1) {
  const uint32_t k0 = 0u, k1 = 1u;                 // jax.random.key(1) -> [0,1]
  const uint32_t k2 = 0x1BD11BDAu ^ k0 ^ k1;
  x0 += k0; x1 += k1;
#define TFR(r) { x0 += x1; x1 = (x1 << (r)) | (x1 >> (32 - (r))); x1 ^= x0; }
  TFR(13) TFR(15) TFR(26) TFR(6)   x0 += k1; x1 += k2 + 1u;
  TFR(17) TFR(29) TFR(16) TFR(24)  x0 += k2; x1 += k0 + 2u;
  TFR(13) TFR(15) TFR(26) TFR(6)   x0 += k0; x1 += k1 + 3u;
  TFR(17) TFR(29) TFR(16) TFR(24)  x0 += k1; x1 += k2 + 4u;
  TFR(13) TFR(15) TFR(26) TFR(6)   x0 += k2; x1 += k0 + 5u;
#undef TFR
  o0 = x0; o1 = x1;
}

__device__ __forceinline__ float z0_at(uint32_t f) {
  uint32_t b;
#if JAX_PARTITIONABLE
  uint32_t o0, o1;
  tf2x32(0u, f, o0, o1);
  b = o0 ^ o1;
#else
  const uint32_t H = 8388608u;
  uint32_t lo = (f < H) ? f : (f - H);
  uint32_t o0, o1;
  tf2x32(lo, lo + H, o0, o1);
  b = (f < H) ? o0 : o1;
#endif
  return __uint_as_float((b >> 9) | 0x3f800000u) - 1.0f;
}

// 4-lane row reduction (lanes xor 1,2 hold one row)
__device__ __forceinline__ float reduce4(float v) {
  v += __shfl_xor(v, 1);
  v += __shfl_xor(v, 2);
  return v;
}

// tree-sum of 16
__device__ __forceinline__ float tsum16(const float* a) {
  float b0 = a[0] + a[1],  b1 = a[2] + a[3],  b2 = a[4] + a[5],
        b3 = a[6] + a[7],  b4 = a[8] + a[9],  b5 = a[10] + a[11],
        b6 = a[12] + a[13], b7 = a[14] + a[15];
  float c0 = b0 + b1, c1 = b2 + b3, c2 = b4 + b5, c3 = b6 + b7;
  return (c0 + c1) + (c2 + c3);
}

#define K1 0.9975f   // 1 - a^2
#define K2 1.9975f   // 2 - a^2

// Collapsed DYS step; returns row sum-sq diff (replicated) if WANT.
template <bool WANT>
__device__ __forceinline__ float dys_step(float z[16], const float ac[16],
                                          float& R) {
  float x[16];
#pragma unroll
  for (int j = 0; j < 16; ++j) x[j] = __builtin_amdgcn_fmed3f(z[j], 0.0f, 1.0f);
  float sx = reduce4(tsum16(x));
  float u    = __builtin_fmaf(K2, sx, -R);
  float corr = __builtin_fmaf(u, 0.015625f, -0.5f);   // (K2*Sx - R - 32)/64
  R = (R - sx) + 32.0f;
  float dsa = 0.0f, dsb = 0.0f;
#pragma unroll
  for (int j = 0; j < 16; ++j) {
    float acpc = ac[j] + corr;
    float zn = __builtin_fmaf(K1, x[j], -acpc);       // z+ = K1*x - (ac+corr)
    if (WANT) {
      float d = zn - z[j];
      if (j & 1) dsb = __builtin_fmaf(d, d, dsb);
      else       dsa = __builtin_fmaf(d, d, dsa);
    }
    z[j] = zn;
  }
  if (!WANT) return 0.0f;
  return reduce4(dsa + dsb);
}

__device__ __forceinline__ void load_ac(const float* __restrict__ cost,
                                        int base, float ac[16]) {
#pragma unroll
  for (int k = 0; k < 4; ++k) {
    const float4 c = *(const float4*)(cost + base + 4 * k);
    ac[4 * k + 0] = 0.05f * c.x; ac[4 * k + 1] = 0.05f * c.y;
    ac[4 * k + 2] = 0.05f * c.z; ac[4 * k + 3] = 0.05f * c.w;
  }
}

template <int STORE>
__global__ __launch_bounds__(256) void dys_pass1(
    const float* __restrict__ cost, int* __restrict__ Tglob,
    int* __restrict__ TrArr, float* __restrict__ zst) {
  const int lane = threadIdx.x & 63;
  const int gw = blockIdx.x * 4 + (threadIdx.x >> 6);       // global wave id
  const int row = gw * ROWS_PER_WAVE + (lane >> 2);
  const int base = row * 64 + (lane & 3) * 16;

  float ac[16], z[16];
  load_ac(cost, base, ac);
  float r0 = 0.0f;
#pragma unroll
  for (int j = 0; j < 16; ++j) {
    z[j] = z0_at((uint32_t)(base + j));
    r0 += z[j] + ac[j];
  }
  float R = reduce4(r0);                                    // Sz0 + a*Sc

  int Tr = 0, ib = MAXIT;
  for (int i = 1; i <= MAXIT; ++i) {
    float ds = dys_step<true>(z, ac, R);
    if (Tr == 0 && ds <= 1.0e-4f) Tr = i;   // ||dz|| <= 0.01
    if (__all(Tr != 0)) { ib = i; break; }  // all 16 rows of the wave done
  }
  // z == lockstep trajectory at iteration ib (wave-uniform)
  if (STORE) {
#pragma unroll
    for (int k = 0; k < 4; ++k)
      *(float4*)(zst + base + 4 * k) =
          make_float4(z[4 * k], z[4 * k + 1], z[4 * k + 2], z[4 * k + 3]);
    if (lane == 0) TrArr[gw] = ib;
  }
  if (lane == 0) atomicMax(Tglob, ib);
}

template <int STORE>
__global__ __launch_bounds__(256) void dys_pass2(
    const float* __restrict__ cost, const int* __restrict__ Tglob,
    const int* __restrict__ TrArr, const float* __restrict__ zst,
    float* __restrict__ out) {
  const int lane = threadIdx.x & 63;
  const int gw = blockIdx.x * 4 + (threadIdx.x >> 6);
  const int row = gw * ROWS_PER_WAVE + (lane >> 2);
  const int base = row * 64 + (lane & 3) * 16;

  float ac[16], z[16];
  load_ac(cost, base, ac);

  const int T = *Tglob;
  int start;
  float R = 0.0f;
  if (STORE) {
#pragma unroll
    for (int k = 0; k < 4; ++k) {
      const float4 zl = *(const float4*)(zst + base + 4 * k);
      z[4 * k] = zl.x; z[4 * k + 1] = zl.y;
      z[4 * k + 2] = zl.z; z[4 * k + 3] = zl.w;
    }
    start = TrArr[gw];             // wave-uniform (stored at wave-break)
    float r0 = 0.0f;
#pragma unroll
    for (int j = 0; j < 16; ++j) r0 += z[j] + ac[j];
    R = reduce4(r0);
  } else {
    float r0 = 0.0f;
#pragma unroll
    for (int j = 0; j < 16; ++j) {
      z[j] = z0_at((uint32_t)(base + j));
      r0 += z[j] + ac[j];
    }
    R = reduce4(r0);
    start = 0;
  }

  for (int i = start; i < T; ++i) dys_step<false>(z, ac, R);

  dys_step<false>(z, ac, R);       // the one differentiable DYS step

  float4 o[4];
#pragma unroll
  for (int k = 0; k < 4; ++k) {
    o[k].x = __builtin_amdgcn_fmed3f(z[4 * k + 0], 0.0f, 1.0f);
    o[k].y = __builtin_amdgcn_fmed3f(z[4 * k + 1], 0.0f, 1.0f);
    o[k].z = __builtin_amdgcn_fmed3f(z[4 * k + 2], 0.0f, 1.0f);
    o[k].w = __builtin_amdgcn_fmed3f(z[4 * k + 3], 0.0f, 1.0f);
    *(float4*)(out + base + 4 * k) = o[k];
  }
}

extern "C" void kernel_launch(void* const* d_in, const int* in_sizes, int n_in,
                              void* d_out, int out_size, void* d_ws,
                              size_t ws_size, hipStream_t stream) {
  const float* cost = (const float*)d_in[0];
  float* out = (float*)d_out;

  int* Tglob = (int*)d_ws;
  const size_t TR_OFF = 1024;
  const size_t Z_OFF  = TR_OFF + (size_t)NWAVES * sizeof(int);
  int*   TrArr = (int*)((char*)d_ws + TR_OFF);
  float* zst   = (float*)((char*)d_ws + Z_OFF);
  const size_t need = Z_OFF + (size_t)BATCHN * 64 * sizeof(float); // ~67 MB
  const bool store = (ws_size >= need);

  hipMemsetAsync(Tglob, 0, sizeof(int), stream);

  dim3 grid(NWAVES / 4), block(256);
  if (store) {
    dys_pass1<1><<<grid, block, 0, stream>>>(cost, Tglob, TrArr, zst);
    dys_pass2<1><<<grid, block, 0, stream>>>(cost, Tglob, TrArr, zst, out);
  } else {
    dys_pass1<0><<<grid, block, 0, stream>>>(cost, Tglob, nullptr, nullptr);
    dys_pass2<0><<<grid, block, 0, stream>>>(cost, Tglob, nullptr, nullptr, out);
  }
}

// Round 6
// 417.670 us; speedup vs baseline: 2.4345x; 1.2243x over previous
//
#include <hip/hip_runtime.h>
#include <cstdint>

// ---------------------------------------------------------------------------
// dysOpt: Davis-Yin splitting, 262144 rows x 64 vars, dynamic T.
//
// u-space collapsed iteration (u = z + C, C = accumulated row correction):
//   m  = med3(u, C, C+1)          (= clamp(z,0,1) + C)
//   Sx = Sm - 64*C
//   corr = (K2*Sx - R - 32)/64 ;  R+ = R - Sx + 32 ;  C+ = K1*C + corr
//   u+ = K1*m - a*c               (independent of reduction -> 2 ops/elem)
// Exact algebra vs reference (z+ = K1*x - a*c - corr); rounding drift is
// damped by the K1=0.9975 contraction (steady state ~1e-4 << bf16 floor).
//
// Structure:
//   probe : 4096 rows, per-iteration checks -> T_s = max Tr (<= T guaranteed)
//   pass1 : all rows; P = max(T_s-3,0) diff-free fast iters, then checked
//           iters to wave all-pass = ib (argmax wave reports exactly T since
//           P+1 < T_s <= T; residual monotone per row); checkpoint z(ib),
//           atomicMax T.
//   pass2 : resume ib -> T, +1 differentiable step, clamp, store.
// ---------------------------------------------------------------------------

#ifndef JAX_PARTITIONABLE
#define JAX_PARTITIONABLE 1
#endif

#define BATCHN 262144
#define MAXIT  200
#define ROWS_PER_WAVE 16
#define NWAVES (BATCHN / ROWS_PER_WAVE)   // 16384
#define PROBE_ROWS 4096
#define PROBE_WAVES (PROBE_ROWS / ROWS_PER_WAVE)  // 256

#define K1 0.9975f   // 1 - a^2
#define K2 1.9975f   // 2 - a^2

__device__ __forceinline__ void tf2x32(uint32_t x0, uint32_t x1,
                                       uint32_t& o0, uint32_t& o1) {
  const uint32_t k0 = 0u, k1 = 1u;                 // jax.random.key(1) -> [0,1]
  const uint32_t k2 = 0x1BD11BDAu ^ k0 ^ k1;
  x0 += k0; x1 += k1;
#define TFR(r) { x0 += x1; x1 = (x1 << (r)) | (x1 >> (32 - (r))); x1 ^= x0; }
  TFR(13) TFR(15) TFR(26) TFR(6)   x0 += k1; x1 += k2 + 1u;
  TFR(17) TFR(29) TFR(16) TFR(24)  x0 += k2; x1 += k0 + 2u;
  TFR(13) TFR(15) TFR(26) TFR(6)   x0 += k0; x1 += k1 + 3u;
  TFR(17) TFR(29) TFR(16) TFR(24)  x0 += k1; x1 += k2 + 4u;
  TFR(13) TFR(15) TFR(26) TFR(6)   x0 += k2; x1 += k0 + 5u;
#undef TFR
  o0 = x0; o1 = x1;
}

__device__ __forceinline__ float z0_at(uint32_t f) {
  uint32_t b;
#if JAX_PARTITIONABLE
  uint32_t o0, o1;
  tf2x32(0u, f, o0, o1);
  b = o0 ^ o1;
#else
  const uint32_t H = 8388608u;
  uint32_t lo = (f < H) ? f : (f - H);
  uint32_t o0, o1;
  tf2x32(lo, lo + H, o0, o1);
  b = (f < H) ? o0 : o1;
#endif
  return __uint_as_float((b >> 9) | 0x3f800000u) - 1.0f;
}

// 4-lane row reduction (lanes xor 1,2 hold one row)
__device__ __forceinline__ float reduce4(float v) {
  v += __shfl_xor(v, 1);
  v += __shfl_xor(v, 2);
  return v;
}

__device__ __forceinline__ float tsum16(const float* a) {
  float b0 = a[0] + a[1],  b1 = a[2] + a[3],  b2 = a[4] + a[5],
        b3 = a[6] + a[7],  b4 = a[8] + a[9],  b5 = a[10] + a[11],
        b6 = a[12] + a[13], b7 = a[14] + a[15];
  float c0 = b0 + b1, c1 = b2 + b3, c2 = b4 + b5, c3 = b6 + b7;
  return (c0 + c1) + (c2 + c3);
}

// u-space DYS step; returns row sum-sq dz (replicated over 4 lanes) if WANT.
template <bool WANT>
__device__ __forceinline__ float u_iter(float u[16], const float ac[16],
                                        float& C, float& Chi, float& R) {
  float m[16];
#pragma unroll
  for (int j = 0; j < 16; ++j) m[j] = __builtin_amdgcn_fmed3f(u[j], C, Chi);
  float Sm = reduce4(tsum16(m));
  float Sx = __builtin_fmaf(-64.0f, C, Sm);
  float t    = __builtin_fmaf(K2, Sx, -R);
  float corr = __builtin_fmaf(t, 0.015625f, -0.5f);   // (K2*Sx - R - 32)/64
  R = (R - Sx) + 32.0f;
  float Cn = __builtin_fmaf(K1, C, corr);
  float dC = Cn - C;                                  // C+ - C (for dz)
  C = Cn; Chi = Cn + 1.0f;
  float dsa = 0.0f, dsb = 0.0f;
#pragma unroll
  for (int j = 0; j < 16; ++j) {
    float un = __builtin_fmaf(K1, m[j], -ac[j]);      // u+ = K1*m - ac
    if (WANT) {
      float d = (un - u[j]) - dC;                     // dz = du - dC
      if (j & 1) dsb = __builtin_fmaf(d, d, dsb);
      else       dsa = __builtin_fmaf(d, d, dsa);
    }
    u[j] = un;
  }
  if (!WANT) return 0.0f;
  return reduce4(dsa + dsb);
}

__device__ __forceinline__ void load_ac(const float* __restrict__ cost,
                                        int base, float ac[16]) {
#pragma unroll
  for (int k = 0; k < 4; ++k) {
    const float4 c = *(const float4*)(cost + base + 4 * k);
    ac[4 * k + 0] = 0.05f * c.x; ac[4 * k + 1] = 0.05f * c.y;
    ac[4 * k + 2] = 0.05f * c.z; ac[4 * k + 3] = 0.05f * c.w;
  }
}

__device__ __forceinline__ void init_state(const float* __restrict__ cost,
                                           int base, float ac[16], float u[16],
                                           float& C, float& Chi, float& R) {
  load_ac(cost, base, ac);
  float r0 = 0.0f;
#pragma unroll
  for (int j = 0; j < 16; ++j) {
    u[j] = z0_at((uint32_t)(base + j));   // u = z0, C = 0
    r0 += u[j] + ac[j];
  }
  C = 0.0f; Chi = 1.0f;
  R = reduce4(r0);                        // R = Sz + a*Sc
}

// --- probe: rows [0, PROBE_ROWS), full checks, atomicMax T_s ---------------
__global__ __launch_bounds__(256) void dys_probe(
    const float* __restrict__ cost, int* __restrict__ Tsample) {
  const int lane = threadIdx.x & 63;
  const int gw = blockIdx.x * 4 + (threadIdx.x >> 6);
  const int base = (gw * ROWS_PER_WAVE + (lane >> 2)) * 64 + (lane & 3) * 16;

  float ac[16], u[16], C, Chi, R;
  init_state(cost, base, ac, u, C, Chi, R);

  int ib = MAXIT;
  for (int i = 1; i <= MAXIT; ++i) {
    float ds = u_iter<true>(u, ac, C, Chi, R);
    if (__all(ds <= 1.0e-4f)) { ib = i; break; }   // wave-max Tr
  }
  if (lane == 0) atomicMax(Tsample, ib);
}

// --- pass1: P fast iters, then checked to wave all-pass; checkpoint --------
__global__ __launch_bounds__(256) void dys_pass1(
    const float* __restrict__ cost, const int* __restrict__ Tsample,
    int* __restrict__ Tglob, int* __restrict__ TrArr,
    float* __restrict__ zst) {
  const int lane = threadIdx.x & 63;
  const int gw = blockIdx.x * 4 + (threadIdx.x >> 6);
  const int base = (gw * ROWS_PER_WAVE + (lane >> 2)) * 64 + (lane & 3) * 16;

  float ac[16], u[16], C, Chi, R;
  init_state(cost, base, ac, u, C, Chi, R);

  const int Ts = *Tsample;                 // uniform -> scalar load
  const int P = (Ts > 3) ? (Ts - 3) : 0;   // P+1 < Ts <= T (safety margin)

  for (int i = 0; i < P; ++i) u_iter<false>(u, ac, C, Chi, R);

  int ib = MAXIT;
  for (int i = P + 1; i <= MAXIT; ++i) {
    float ds = u_iter<true>(u, ac, C, Chi, R);
    if (__all(ds <= 1.0e-4f)) { ib = i; break; }
  }
  // ib = max(wave-max Tr, P+1) <= T; argmax wave reports exactly T.

  // checkpoint z(ib) = u - C
#pragma unroll
  for (int k = 0; k < 4; ++k) {
    float4 zq;
    zq.x = u[4 * k + 0] - C; zq.y = u[4 * k + 1] - C;
    zq.z = u[4 * k + 2] - C; zq.w = u[4 * k + 3] - C;
    *(float4*)(zst + base + 4 * k) = zq;
  }
  if (lane == 0) {
    TrArr[gw] = ib;
    atomicMax(Tglob, ib);
  }
}

// --- pass2: resume ib -> T, +1 differentiable step, clamp, store -----------
__global__ __launch_bounds__(256) void dys_pass2(
    const float* __restrict__ cost, const int* __restrict__ Tglob,
    const int* __restrict__ TrArr, const float* __restrict__ zst,
    float* __restrict__ out) {
  const int lane = threadIdx.x & 63;
  const int gw = blockIdx.x * 4 + (threadIdx.x >> 6);
  const int base = (gw * ROWS_PER_WAVE + (lane >> 2)) * 64 + (lane & 3) * 16;

  float ac[16], u[16];
  load_ac(cost, base, ac);
  float r0 = 0.0f;
#pragma unroll
  for (int k = 0; k < 4; ++k) {
    const float4 zq = *(const float4*)(zst + base + 4 * k);
    u[4 * k + 0] = zq.x; u[4 * k + 1] = zq.y;
    u[4 * k + 2] = zq.z; u[4 * k + 3] = zq.w;
  }
#pragma unroll
  for (int j = 0; j < 16; ++j) r0 += u[j] + ac[j];
  float C = 0.0f, Chi = 1.0f;
  float R = reduce4(r0);                   // R = Sz + a*Sc (invariant)

  const int T = *Tglob;
  const int ib = TrArr[gw];                // wave-uniform

  // (T - ib) lockstep iters to reach z(T), +1 differentiable step
  for (int i = ib; i <= T; ++i) u_iter<false>(u, ac, C, Chi, R);

#pragma unroll
  for (int k = 0; k < 4; ++k) {
    float4 o;
    o.x = __builtin_amdgcn_fmed3f(u[4 * k + 0] - C, 0.0f, 1.0f);
    o.y = __builtin_amdgcn_fmed3f(u[4 * k + 1] - C, 0.0f, 1.0f);
    o.z = __builtin_amdgcn_fmed3f(u[4 * k + 2] - C, 0.0f, 1.0f);
    o.w = __builtin_amdgcn_fmed3f(u[4 * k + 3] - C, 0.0f, 1.0f);
    *(float4*)(out + base + 4 * k) = o;
  }
}

extern "C" void kernel_launch(void* const* d_in, const int* in_sizes, int n_in,
                              void* d_out, int out_size, void* d_ws,
                              size_t ws_size, hipStream_t stream) {
  const float* cost = (const float*)d_in[0];
  float* out = (float*)d_out;

  // ws: [0..4) Tglob ; [4..8) Tsample ; [1024..) TrArr ; then z checkpoint
  int* Tglob   = (int*)d_ws;
  int* Tsample = (int*)d_ws + 1;
  const size_t TR_OFF = 1024;
  const size_t Z_OFF  = TR_OFF + (size_t)NWAVES * sizeof(int);
  int*   TrArr = (int*)((char*)d_ws + TR_OFF);
  float* zst   = (float*)((char*)d_ws + Z_OFF);

  hipMemsetAsync(d_ws, 0, 8, stream);   // Tglob = Tsample = 0

  dim3 block(256);
  dys_probe<<<dim3(PROBE_WAVES / 4), block, 0, stream>>>(cost, Tsample);
  dys_pass1<<<dim3(NWAVES / 4), block, 0, stream>>>(cost, Tsample, Tglob,
                                                    TrArr, zst);
  dys_pass2<<<dim3(NWAVES / 4), block, 0, stream>>>(cost, Tglob, TrArr, zst,
                                                    out);
}